// Round 1
// baseline (4886.356 us; speedup 1.0000x reference)
//
#include <hip/hip_runtime.h>
#include <math.h>

// Problem constants (fixed by setup_inputs)
#define NB 64
#define NC 256
#define NHW 16
#define NE 8192
#define NUMEL 4194304          // 64*256*16*16
#define LOSS_OFF 4194304
#define CNT_OFF  4194305

// ---------------- helpers ----------------
__device__ __forceinline__ float cubicw(float t) {
  // torch bicubic, a = -0.75
  t = fabsf(t);
  if (t <= 1.0f) return (1.25f * t - 2.25f) * t * t + 1.0f;
  if (t < 2.0f)  return ((-0.75f * t + 3.75f) * t - 6.0f) * t + 3.0f;
  return 0.0f;
}

// ---------------- prep kernels ----------------
// zero d_out (z_hat region + loss + counts) and z_hat accumulator
__global__ void k_zero(float* a, int na, float* b, int nb) {
  int stride = gridDim.x * 256;
  for (int i = blockIdx.x * 256 + threadIdx.x; i < na + nb; i += stride) {
    if (i < na) a[i] = 0.0f; else b[i - na] = 0.0f;
  }
}

// z (NCHW) -> z_rest, z_nhwc (both NHWC [16384][256])
__global__ void k_tr_in(const float* __restrict__ z, float* __restrict__ zrest,
                        float* __restrict__ znh) {
  int n = blockIdx.x, c = threadIdx.x;
  int b = n >> 8, hw = n & 255;
  float v = z[((size_t)(b * 256 + c)) * 256 + hw];
  zrest[(size_t)n * 256 + c] = v;
  znh[(size_t)n * 256 + c] = v;
}

// embedding [8192][256] -> embT [256][8192] and e_sq[8192]
__global__ void k_prep_emb(const float* __restrict__ emb, float* __restrict__ embT,
                           float* __restrict__ esq) {
  int j = blockIdx.x, t = threadIdx.x;
  float v = emb[(size_t)j * 256 + t];
  embT[(size_t)t * 8192 + j] = v;
  __shared__ float red[256];
  red[t] = v * v;
  __syncthreads();
  for (int s = 128; s > 0; s >>= 1) { if (t < s) red[t] += red[t + s]; __syncthreads(); }
  if (t == 0) esq[j] = red[0];
}

// conv_w [si][o][i][kh][kw] -> wT [si][kh][kw][i][o]
__global__ void k_prep_w(const float* __restrict__ w, float* __restrict__ wT) {
  int m = blockIdx.x * 256 + threadIdx.x;
  if (m >= 8 * 9 * 65536) return;
  int o = m & 255, i = (m >> 8) & 255;
  int r = m >> 16;            // si*9 + kh*3 + kw
  int si = r / 9, k9 = r % 9;
  wT[m] = w[(((size_t)si * 256 + o) * 256 + i) * 9 + k9];
}

// ---------------- per-scale kernels ----------------
// area downsample: z_rest NHWC -> zd [B*pn*pn][256]
__global__ void k_down(const float* __restrict__ zrest, float* __restrict__ zd, int pn) {
  int pq = blockIdx.x, b = blockIdx.y, c = threadIdx.x;
  int p = pq / pn, q = pq % pn;
  int sp = (p * 16) / pn, ep = ((p + 1) * 16 + pn - 1) / pn;
  int sq = (q * 16) / pn, eq = ((q + 1) * 16 + pn - 1) / pn;
  float s = 0.0f;
  for (int h = sp; h < ep; h++)
    for (int w = sq; w < eq; w++)
      s += zrest[((size_t)((b * 16 + h) * 16 + w)) * 256 + c];
  zd[((size_t)(b * pn + p) * pn + q) * 256 + c] = s / (float)((ep - sp) * (eq - sq));
}

// fused distance + per-tile argmin.
// block: ROWS rows x CT codes. 256 thr; wave q handles rows [q*RT, q*RT+RT),
// lane l handles codes jb+l (+64,+128,+192) per 256-code chunk.
template <int ROWS>
__global__ __launch_bounds__(256) void k_dist(const float* __restrict__ zd,
    const float* __restrict__ embT, const float* __restrict__ esq,
    float* __restrict__ pd, int* __restrict__ pi, int N, int CT, int nct) {
  constexpr int RT = ROWS / 4;
  __shared__ float a_s[ROWS][260];
  int t = threadIdx.x, l = t & 63, q = t >> 6;
  int n0 = blockIdx.x * ROWS, jt = blockIdx.y;
  for (int e4 = t * 4; e4 < ROWS * 256; e4 += 1024) {
    int r = e4 >> 8, c = e4 & 255;
    float4 v = make_float4(0.f, 0.f, 0.f, 0.f);
    if (n0 + r < N) v = *(const float4*)(zd + (size_t)(n0 + r) * 256 + c);
    *(float4*)&a_s[r][c] = v;
  }
  __syncthreads();
  float best[RT]; int bidx[RT];
#pragma unroll
  for (int rr = 0; rr < RT; rr++) { best[rr] = 3.4e38f; bidx[rr] = 0; }
  int nch = CT >> 8;
  for (int ch = 0; ch < nch; ch++) {
    int jb = jt * CT + ch * 256 + l;
    float acc[4][RT];
#pragma unroll
    for (int cc = 0; cc < 4; cc++)
#pragma unroll
      for (int rr = 0; rr < RT; rr++) acc[cc][rr] = 0.0f;
    for (int c4 = 0; c4 < 256; c4 += 4) {
      float bv[4][4];
#pragma unroll
      for (int ci = 0; ci < 4; ci++)
#pragma unroll
        for (int cc = 0; cc < 4; cc++)
          bv[ci][cc] = embT[(size_t)(c4 + ci) * 8192 + jb + cc * 64];
#pragma unroll
      for (int rr = 0; rr < RT; rr++) {
        float4 a4 = *(const float4*)&a_s[q * RT + rr][c4];
#pragma unroll
        for (int cc = 0; cc < 4; cc++) {
          acc[cc][rr] += a4.x * bv[0][cc];
          acc[cc][rr] += a4.y * bv[1][cc];
          acc[cc][rr] += a4.z * bv[2][cc];
          acc[cc][rr] += a4.w * bv[3][cc];
        }
      }
    }
#pragma unroll
    for (int cc = 0; cc < 4; cc++) {
      int j = jb + cc * 64;
      float es = esq[j];
#pragma unroll
      for (int rr = 0; rr < RT; rr++) {
        float d = es - 2.0f * acc[cc][rr];
        if (d < best[rr] || (d == best[rr] && j < bidx[rr])) { best[rr] = d; bidx[rr] = j; }
      }
    }
  }
  // wave-level argmin reduce (64 lanes share the same rows)
#pragma unroll
  for (int rr = 0; rr < RT; rr++) {
    float bd = best[rr]; int bi = bidx[rr];
    for (int off = 1; off < 64; off <<= 1) {
      float od = __shfl_xor(bd, off, 64);
      int   oi = __shfl_xor(bi, off, 64);
      if (od < bd || (od == bd && oi < bi)) { bd = od; bi = oi; }
    }
    if (l == 0) {
      int n = n0 + q * RT + rr;
      if (n < N) { pd[(size_t)n * nct + jt] = bd; pi[(size_t)n * nct + jt] = bi; }
    }
  }
}

// reduce per-row partials over code tiles -> idx, counts
__global__ void k_red(const float* __restrict__ pd, const int* __restrict__ pi,
                      int* __restrict__ idxb, float* __restrict__ counts, int N, int nct) {
  int n = blockIdx.x * 256 + threadIdx.x;
  if (n >= N) return;
  float bd = pd[(size_t)n * nct]; int bi = pi[(size_t)n * nct];
  for (int jt = 1; jt < nct; jt++) {
    float d = pd[(size_t)n * nct + jt]; int ii = pi[(size_t)n * nct + jt];
    if (d < bd || (d == bd && ii < bi)) { bd = d; bi = ii; }
  }
  idxb[n] = bi;
  atomicAdd(counts + bi, 1.0f);
}

// gather + bicubic upsample -> zu NHWC [16384][256]
__global__ void k_up(const float* __restrict__ emb, const int* __restrict__ idxb,
                     float* __restrict__ zu, int pn, int last) {
  int n = blockIdx.x, c = threadIdx.x;
  if (last) { zu[(size_t)n * 256 + c] = emb[(size_t)idxb[n] * 256 + c]; return; }
  int b = n >> 8, hw = n & 255, h = hw >> 4, w = hw & 15;
  float scale = pn / 16.0f;
  float xh = (h + 0.5f) * scale - 0.5f; int fh = (int)floorf(xh);
  float xw = (w + 0.5f) * scale - 0.5f; int fw = (int)floorf(xw);
  int ph[4], pw[4]; float wh[4], wwt[4];
#pragma unroll
  for (int k = 0; k < 4; k++) {
    wh[k] = cubicw(xh - (float)(fh + k - 1));
    int pp = fh + k - 1; ph[k] = min(max(pp, 0), pn - 1);
    wwt[k] = cubicw(xw - (float)(fw + k - 1));
    pp = fw + k - 1; pw[k] = min(max(pp, 0), pn - 1);
  }
  float acc = 0.0f;
#pragma unroll
  for (int kh = 0; kh < 4; kh++)
#pragma unroll
    for (int kw = 0; kw < 4; kw++) {
      int row = idxb[(b * pn + ph[kh]) * pn + pw[kw]];
      acc += wh[kh] * wwt[kw] * emb[(size_t)row * 256 + c];
    }
  zu[(size_t)n * 256 + c] = acc;
}

// 3x3 SAME conv (NHWC) + fused residual update + loss partial.
// block: (hp, b) -> 2 output rows x 16 w x 256 o. thread: 4 o x (2 r x 4 w).
__global__ __launch_bounds__(256) void k_conv(
    const float* __restrict__ zu, const float* __restrict__ wT,
    const float* __restrict__ cb, const float* __restrict__ znh,
    float* __restrict__ zhat, float* __restrict__ zrest,
    float* __restrict__ out_loss, int si) {
  __shared__ float zs[4 * 16 * 256];
  __shared__ float red[256];
  int t = threadIdx.x;
  int hp = blockIdx.x, b = blockIdx.y;
  int h0 = hp * 2;
  // stage rows h0-1..h0+2 (zero-padded)
  for (int e4 = t * 4; e4 < 16384; e4 += 1024) {
    int sr = e4 >> 12, rem = e4 & 4095;
    int grow = h0 - 1 + sr;
    float4 v = make_float4(0.f, 0.f, 0.f, 0.f);
    if (grow >= 0 && grow < 16)
      v = *(const float4*)(zu + ((size_t)(b * 16 + grow) * 16) * 256 + rem);
    *(float4*)&zs[e4] = v;
  }
  __syncthreads();
  int ot = t & 63, st = t >> 6;
  int o0 = ot * 4, w0 = st * 4;
  float4 acc[2][4];
#pragma unroll
  for (int rr = 0; rr < 2; rr++)
#pragma unroll
    for (int ww = 0; ww < 4; ww++) acc[rr][ww] = make_float4(0.f, 0.f, 0.f, 0.f);
  const float* wbase = wT + (size_t)si * 9 * 65536;
  for (int i = 0; i < 256; i++) {
    float zr[4][6];
#pragma unroll
    for (int sr = 0; sr < 4; sr++)
#pragma unroll
      for (int ww = 0; ww < 6; ww++) {
        int wp = w0 + ww - 1;
        zr[sr][ww] = (wp >= 0 && wp < 16) ? zs[sr * 4096 + wp * 256 + i] : 0.0f;
      }
#pragma unroll
    for (int kh = 0; kh < 3; kh++) {
      float4 wv[3];
#pragma unroll
      for (int kw = 0; kw < 3; kw++)
        wv[kw] = *(const float4*)(wbase + ((size_t)(kh * 3 + kw) * 256 + i) * 256 + o0);
#pragma unroll
      for (int kw = 0; kw < 3; kw++)
#pragma unroll
        for (int rr = 0; rr < 2; rr++)
#pragma unroll
          for (int ww = 0; ww < 4; ww++) {
            float zv = zr[rr + kh][ww + kw];
            acc[rr][ww].x += zv * wv[kw].x;
            acc[rr][ww].y += zv * wv[kw].y;
            acc[rr][ww].z += zv * wv[kw].z;
            acc[rr][ww].w += zv * wv[kw].w;
          }
    }
  }
  float4 bias = *(const float4*)(cb + si * 256 + o0);
  float lsum = 0.0f;
#pragma unroll
  for (int rr = 0; rr < 2; rr++)
#pragma unroll
    for (int ww = 0; ww < 4; ww++) {
      int h = h0 + rr, w = w0 + ww;
      size_t n = ((size_t)(b * 16 + h) * 16 + w) * 256 + o0;
      float4 zuv = *(float4*)&zs[(rr + 1) * 4096 + w * 256 + o0];
      float4 y;
      y.x = acc[rr][ww].x + bias.x; y.y = acc[rr][ww].y + bias.y;
      y.z = acc[rr][ww].z + bias.z; y.w = acc[rr][ww].w + bias.w;
      float4 res;
      res.x = 0.5f * (zuv.x + y.x); res.y = 0.5f * (zuv.y + y.y);
      res.z = 0.5f * (zuv.z + y.z); res.w = 0.5f * (zuv.w + y.w);
      float4 zh = *(float4*)(zhat + n);
      zh.x += res.x; zh.y += res.y; zh.z += res.z; zh.w += res.w;
      *(float4*)(zhat + n) = zh;
      float4 zz = *(const float4*)(znh + n);
      float dx = zh.x - zz.x, dy = zh.y - zz.y, dz = zh.z - zz.z, dw = zh.w - zz.w;
      lsum += dx * dx + dy * dy + dz * dz + dw * dw;
      float4 zr4 = *(float4*)(zrest + n);
      zr4.x -= res.x; zr4.y -= res.y; zr4.z -= res.z; zr4.w -= res.w;
      *(float4*)(zrest + n) = zr4;
    }
  red[t] = lsum;
  __syncthreads();
  for (int s = 128; s > 0; s >>= 1) { if (t < s) red[t] += red[t + s]; __syncthreads(); }
  if (t == 0) atomicAdd(out_loss, red[0] * (0.25f / (8.0f * 4194304.0f)));
}

// z_hat NHWC -> d_out NCHW
__global__ void k_out(const float* __restrict__ zhat, float* __restrict__ out) {
  int n = blockIdx.x, c = threadIdx.x;
  int b = n >> 8, hw = n & 255;
  out[((size_t)(b * 256 + c)) * 256 + hw] = zhat[(size_t)n * 256 + c];
}

// ---------------- launch ----------------
extern "C" void kernel_launch(void* const* d_in, const int* in_sizes, int n_in,
                              void* d_out, int out_size, void* d_ws, size_t ws_size,
                              hipStream_t stream) {
  const float* z   = (const float*)d_in[0];
  const float* emb = (const float*)d_in[1];
  const float* cw  = (const float*)d_in[2];
  const float* cb  = (const float*)d_in[3];
  float* out = (float*)d_out;
  float* ws  = (float*)d_ws;

  float* z_rest = ws;                      // 4194304
  float* z_nh   = ws + 4194304;            // 4194304
  float* z_hat  = ws + 8388608;            // 4194304
  float* zd     = ws + 12582912;           // 4194304
  float* zu     = ws + 16777216;           // 4194304
  float* embT   = ws + 20971520;           // 2097152
  float* esq    = ws + 23068672;           // 8192
  float* wT     = ws + 23076864;           // 4718592
  int*   idxb   = (int*)(ws + 27795456);   // 16384
  float* pd     = ws + 27811840;           // 65536
  int*   pi     = (int*)(ws + 27877376);   // 65536

  const int pns[8]  = {1, 2, 3, 4, 6, 8, 12, 16};
  const int Rv[8]   = {16, 16, 16, 16, 64, 64, 64, 64};
  const int nctv[8] = {32, 32, 16, 8, 8, 8, 4, 2};

  k_zero<<<8192, 256, 0, stream>>>(out, 4202497, z_hat, NUMEL);
  k_tr_in<<<16384, 256, 0, stream>>>(z, z_rest, z_nh);
  k_prep_emb<<<8192, 256, 0, stream>>>(emb, embT, esq);
  k_prep_w<<<4718592 / 256, 256, 0, stream>>>(cw, wT);

  for (int si = 0; si < 8; si++) {
    int pn = pns[si];
    int N = 64 * pn * pn;
    const float* zdp;
    if (si < 7) {
      k_down<<<dim3(pn * pn, 64), 256, 0, stream>>>(z_rest, zd, pn);
      zdp = zd;
    } else {
      zdp = z_rest;   // identity: z_rest NHWC is exactly [N][C] row order
    }
    int R = Rv[si], nct = nctv[si], CT = 8192 / nct, rt = (N + R - 1) / R;
    if (R == 16)
      k_dist<16><<<dim3(rt, nct), 256, 0, stream>>>(zdp, embT, esq, pd, pi, N, CT, nct);
    else
      k_dist<64><<<dim3(rt, nct), 256, 0, stream>>>(zdp, embT, esq, pd, pi, N, CT, nct);
    k_red<<<(N + 255) / 256, 256, 0, stream>>>(pd, pi, idxb, out + CNT_OFF, N, nct);
    k_up<<<16384, 256, 0, stream>>>(emb, idxb, zu, pn, si == 7 ? 1 : 0);
    k_conv<<<dim3(8, 64), 256, 0, stream>>>(zu, wT, cb, z_nh, z_hat, z_rest,
                                            out + LOSS_OFF, si);
  }
  k_out<<<16384, 256, 0, stream>>>(z_hat, out);
}

// Round 5
// 3940.270 us; speedup vs baseline: 1.2401x; 1.2401x over previous
//
#include <hip/hip_runtime.h>
#include <math.h>

// Problem constants (fixed by setup_inputs)
#define NB 64
#define NC 256
#define NHW 16
#define NE 8192
#define NUMEL 4194304          // 64*256*16*16
#define LOSS_OFF 4194304
#define CNT_OFF  4194305

typedef __bf16 bf16x8 __attribute__((ext_vector_type(8)));
typedef float  f32x4  __attribute__((ext_vector_type(4)));

// ---------------- helpers ----------------
__device__ __forceinline__ float cubicw(float t) {
  // torch bicubic, a = -0.75
  t = fabsf(t);
  if (t <= 1.0f) return (1.25f * t - 2.25f) * t * t + 1.0f;
  if (t < 2.0f)  return ((-0.75f * t + 3.75f) * t - 6.0f) * t + 3.0f;
  return 0.0f;
}

__device__ __forceinline__ short f2bf(float x) {
  union { float f; unsigned int u; } v; v.f = x;
  unsigned int r = v.u + 0x7fffu + ((v.u >> 16) & 1u);  // RNE
  return (short)(r >> 16);
}
__device__ __forceinline__ float bf2f(short h) {
  union { float f; unsigned int u; } v;
  v.u = ((unsigned int)(unsigned short)h) << 16;
  return v.f;
}

// ---------------- prep kernels ----------------
// zero loss + counts region of d_out
__global__ void k_zero(float* a, int na) {
  int i = blockIdx.x * 256 + threadIdx.x;
  if (i < na) a[i] = 0.0f;
}

// z (NCHW) -> z_rest NHWC [16384][256]
__global__ void k_tr_in(const float* __restrict__ z, float* __restrict__ zrest) {
  int n = blockIdx.x, c = threadIdx.x;
  int b = n >> 8, hw = n & 255;
  zrest[(size_t)n * 256 + c] = z[((size_t)(b * 256 + c)) * 256 + hw];
}

// embedding [8192][256] -> B2 [8192][768] bf16 rows = [hi, hi, lo]; esq[8192] fp32
__global__ void k_prep_emb2(const float* __restrict__ emb, short* __restrict__ B2,
                            float* __restrict__ esq) {
  int j = blockIdx.x, t = threadIdx.x;
  float v = emb[(size_t)j * 256 + t];
  short hi = f2bf(v);
  short lo = f2bf(v - bf2f(hi));
  B2[(size_t)j * 768 + t]       = hi;
  B2[(size_t)j * 768 + 256 + t] = hi;
  B2[(size_t)j * 768 + 512 + t] = lo;
  __shared__ float red[256];
  red[t] = v * v;
  __syncthreads();
  for (int s = 128; s > 0; s >>= 1) { if (t < s) red[t] += red[t + s]; __syncthreads(); }
  if (t == 0) esq[j] = red[0];
}

// conv_w [si][o][i][kh][kw] -> wT [si][kh][kw][i][o]
__global__ void k_prep_w(const float* __restrict__ w, float* __restrict__ wT) {
  int m = blockIdx.x * 256 + threadIdx.x;
  if (m >= 8 * 9 * 65536) return;
  int o = m & 255, i = (m >> 8) & 255;
  int r = m >> 16;            // si*9 + kh*3 + kw
  int si = r / 9, k9 = r % 9;
  wT[m] = w[(((size_t)si * 256 + o) * 256 + i) * 9 + k9];
}

// ---------------- per-scale kernels ----------------
// area downsample: z_rest NHWC -> A2 rows [hi, lo, hi]
__global__ void k_down_a2(const float* __restrict__ zrest, short* __restrict__ A2, int pn) {
  int pq = blockIdx.x, b = blockIdx.y, c = threadIdx.x;
  int p = pq / pn, q = pq % pn;
  int sp = (p * 16) / pn, ep = ((p + 1) * 16 + pn - 1) / pn;
  int sq = (q * 16) / pn, eq = ((q + 1) * 16 + pn - 1) / pn;
  float s = 0.0f;
  for (int h = sp; h < ep; h++)
    for (int w = sq; w < eq; w++)
      s += zrest[((size_t)((b * 16 + h) * 16 + w)) * 256 + c];
  float x = s / (float)((ep - sp) * (eq - sq));
  int n = (b * pn + p) * pn + q;
  short hi = f2bf(x);
  short lo = f2bf(x - bf2f(hi));
  A2[(size_t)n * 768 + c]       = hi;
  A2[(size_t)n * 768 + 256 + c] = lo;
  A2[(size_t)n * 768 + 512 + c] = hi;
}

// identity (last scale): z_rest NHWC -> A2
__global__ void k_split_a2(const float* __restrict__ zrest, short* __restrict__ A2) {
  int n = blockIdx.x, c = threadIdx.x;
  float x = zrest[(size_t)n * 256 + c];
  short hi = f2bf(x);
  short lo = f2bf(x - bf2f(hi));
  A2[(size_t)n * 768 + c]       = hi;
  A2[(size_t)n * 768 + 256 + c] = lo;
  A2[(size_t)n * 768 + 512 + c] = hi;
}

// MFMA distance GEMM + fused argmin over 512 codes per block.
// C[n][j] = A2[n]·B2[j] (K=768 compensated bf16) ; dist = esq[j] - 2C.
// Block: 128 rows x (4 x 128 codes), 256 thr = 4 waves (2x2 of 64x64).
// R5 fix: waves wc=0/1 hold argmin over DIFFERENT 64-code halves of the same
// rows; R2-R4 raced both into pd[n] (last writer wins -> half the codes
// dropped per tile). Combine the two halves through LDS before the write.
#define LDA 72
__global__ __launch_bounds__(256) void k_dist_mfma(
    const short* __restrict__ A2, const short* __restrict__ B2,
    const float* __restrict__ esq, float* __restrict__ pd, int* __restrict__ pi,
    int N) {
  __shared__ short As[128 * LDA];
  __shared__ short Bs[128 * LDA];
  __shared__ float sbd[2][128];
  __shared__ int   sbi[2][128];
  int t = threadIdx.x, ln = t & 63, wv = t >> 6;
  int wr = wv >> 1, wc = wv & 1;
  int n0 = blockIdx.x * 128;
  int lc = ln & 15, lq = ln >> 4;

  float best[4][4]; int bidx[4][4];
#pragma unroll
  for (int rt = 0; rt < 4; rt++)
#pragma unroll
    for (int r = 0; r < 4; r++) { best[rt][r] = 3.4e38f; bidx[rt][r] = 0; }

  for (int jt2 = 0; jt2 < 4; jt2++) {
    int jb0 = (blockIdx.y * 4 + jt2) * 128;
    f32x4 acc[4][4];
#pragma unroll
    for (int a = 0; a < 4; a++)
#pragma unroll
      for (int b = 0; b < 4; b++) acc[a][b] = (f32x4)(0.0f);

    for (int kk = 0; kk < 768; kk += 64) {
      // stage 128 rows x 64 shorts for A and B (16B per thread per buffer per step)
#pragma unroll
      for (int i = 0; i < 4; i++) {
        int G = i * 256 + t;          // group of 8 shorts
        int row = G >> 3, cc = G & 7;
        uint4 va = *(const uint4*)(A2 + (size_t)(n0 + row) * 768 + kk + cc * 8);
        *(uint4*)(As + row * LDA + cc * 8) = va;
        uint4 vb = *(const uint4*)(B2 + (size_t)(jb0 + row) * 768 + kk + cc * 8);
        *(uint4*)(Bs + row * LDA + cc * 8) = vb;
      }
      __syncthreads();
#pragma unroll
      for (int ks = 0; ks < 2; ks++) {
        bf16x8 fa[4], fb[4];
#pragma unroll
        for (int rt = 0; rt < 4; rt++) {
          int row = wr * 64 + rt * 16 + lc;
          fa[rt] = *(const bf16x8*)(As + row * LDA + (ks * 4 + lq) * 8);
        }
#pragma unroll
        for (int ct = 0; ct < 4; ct++) {
          int row = wc * 64 + ct * 16 + lc;
          fb[ct] = *(const bf16x8*)(Bs + row * LDA + (ks * 4 + lq) * 8);
        }
#pragma unroll
        for (int rt = 0; rt < 4; rt++)
#pragma unroll
          for (int ct = 0; ct < 4; ct++)
            acc[rt][ct] = __builtin_amdgcn_mfma_f32_16x16x32_bf16(
                fa[rt], fb[ct], acc[rt][ct], 0, 0, 0);
      }
      __syncthreads();
    }

    // fold this subtile into the running per-row argmin (registers only).
    // jt2 ascending + ct ascending => strict '<' keeps the lowest index on ties.
#pragma unroll
    for (int rt = 0; rt < 4; rt++)
#pragma unroll
      for (int ct = 0; ct < 4; ct++) {
        int j = jb0 + wc * 64 + ct * 16 + lc;
        float es = esq[j];
#pragma unroll
        for (int r = 0; r < 4; r++) {
          float d = es - 2.0f * acc[rt][ct][r];
          if (d < best[rt][r]) { best[rt][r] = d; bidx[rt][r] = j; }
        }
      }
  }

  // cross-lane argmin over the 16 cols held by this lane group -> LDS.
#pragma unroll
  for (int rt = 0; rt < 4; rt++) {
#pragma unroll
    for (int r = 0; r < 4; r++) {
      float bd = best[rt][r]; int bi = bidx[rt][r];
#pragma unroll
      for (int off = 1; off < 16; off <<= 1) {
        float od = __shfl_xor(bd, off, 64);
        int   oi = __shfl_xor(bi, off, 64);
        if (od < bd || (od == bd && oi < bi)) { bd = od; bi = oi; }
      }
      if (lc == 0) {
        int rloc = wr * 64 + rt * 16 + lq * 4 + r;
        sbd[wc][rloc] = bd;
        sbi[wc][rloc] = bi;
      }
    }
  }
  __syncthreads();
  // combine the two code-halves (wc=0 holds lower j: strict '<' keeps ties low)
  if (t < 128) {
    float b0 = sbd[0][t]; int i0 = sbi[0][t];
    float b1 = sbd[1][t]; int i1 = sbi[1][t];
    if (b1 < b0 || (b1 == b0 && i1 < i0)) { b0 = b1; i0 = i1; }
    int n = n0 + t;
    if (n < N) {
      pd[(size_t)n * 16 + blockIdx.y] = b0;
      pi[(size_t)n * 16 + blockIdx.y] = i0;
    }
  }
}

// reduce per-row partials over 16 code tiles -> idx, counts
__global__ void k_red(const float* __restrict__ pd, const int* __restrict__ pi,
                      int* __restrict__ idxb, float* __restrict__ counts, int N, int nct) {
  int n = blockIdx.x * 256 + threadIdx.x;
  if (n >= N) return;
  float bd = pd[(size_t)n * nct]; int bi = pi[(size_t)n * nct];
  for (int jt = 1; jt < nct; jt++) {
    float d = pd[(size_t)n * nct + jt]; int ii = pi[(size_t)n * nct + jt];
    if (d < bd || (d == bd && ii < bi)) { bd = d; bi = ii; }
  }
  idxb[n] = bi;
  atomicAdd(counts + bi, 1.0f);
}

// gather + bicubic upsample -> zu NHWC [16384][256]
__global__ void k_up(const float* __restrict__ emb, const int* __restrict__ idxb,
                     float* __restrict__ zu, int pn, int last) {
  int n = blockIdx.x, c = threadIdx.x;
  if (last) { zu[(size_t)n * 256 + c] = emb[(size_t)idxb[n] * 256 + c]; return; }
  int b = n >> 8, hw = n & 255, h = hw >> 4, w = hw & 15;
  float scale = pn / 16.0f;
  float xh = (h + 0.5f) * scale - 0.5f; int fh = (int)floorf(xh);
  float xw = (w + 0.5f) * scale - 0.5f; int fw = (int)floorf(xw);
  int ph[4], pw[4]; float wh[4], wwt[4];
#pragma unroll
  for (int k = 0; k < 4; k++) {
    wh[k] = cubicw(xh - (float)(fh + k - 1));
    int pp = fh + k - 1; ph[k] = min(max(pp, 0), pn - 1);
    wwt[k] = cubicw(xw - (float)(fw + k - 1));
    pp = fw + k - 1; pw[k] = min(max(pp, 0), pn - 1);
  }
  float acc = 0.0f;
#pragma unroll
  for (int kh = 0; kh < 4; kh++)
#pragma unroll
    for (int kw = 0; kw < 4; kw++) {
      int row = idxb[(b * pn + ph[kh]) * pn + pw[kw]];
      acc += wh[kh] * wwt[kw] * emb[(size_t)row * 256 + c];
    }
  zu[(size_t)n * 256 + c] = acc;
}

// 3x3 SAME conv (NHWC) + fused residual update + loss partial.
// z_hat is implicit: z_hat_cum = z - z_rest, so loss term = mean(z_rest_new^2).
__global__ __launch_bounds__(256) void k_conv(
    const float* __restrict__ zu, const float* __restrict__ wT,
    const float* __restrict__ cb, float* __restrict__ zrest,
    float* __restrict__ out_loss, int si) {
  __shared__ float zs[4 * 16 * 256];
  __shared__ float red[256];
  int t = threadIdx.x;
  int hp = blockIdx.x, b = blockIdx.y;
  int h0 = hp * 2;
  for (int e4 = t * 4; e4 < 16384; e4 += 1024) {
    int sr = e4 >> 12, rem = e4 & 4095;
    int grow = h0 - 1 + sr;
    float4 v = make_float4(0.f, 0.f, 0.f, 0.f);
    if (grow >= 0 && grow < 16)
      v = *(const float4*)(zu + ((size_t)(b * 16 + grow) * 16) * 256 + rem);
    *(float4*)&zs[e4] = v;
  }
  __syncthreads();
  int ot = t & 63, st = t >> 6;
  int o0 = ot * 4, w0 = st * 4;
  float4 acc[2][4];
#pragma unroll
  for (int rr = 0; rr < 2; rr++)
#pragma unroll
    for (int ww = 0; ww < 4; ww++) acc[rr][ww] = make_float4(0.f, 0.f, 0.f, 0.f);
  const float* wbase = wT + (size_t)si * 9 * 65536;
  for (int i = 0; i < 256; i++) {
    float zr[4][6];
#pragma unroll
    for (int sr = 0; sr < 4; sr++)
#pragma unroll
      for (int ww = 0; ww < 6; ww++) {
        int wp = w0 + ww - 1;
        zr[sr][ww] = (wp >= 0 && wp < 16) ? zs[sr * 4096 + wp * 256 + i] : 0.0f;
      }
#pragma unroll
    for (int kh = 0; kh < 3; kh++) {
      float4 wv[3];
#pragma unroll
      for (int kw = 0; kw < 3; kw++)
        wv[kw] = *(const float4*)(wbase + ((size_t)(kh * 3 + kw) * 256 + i) * 256 + o0);
#pragma unroll
      for (int kw = 0; kw < 3; kw++)
#pragma unroll
        for (int rr = 0; rr < 2; rr++)
#pragma unroll
          for (int ww = 0; ww < 4; ww++) {
            float zv = zr[rr + kh][ww + kw];
            acc[rr][ww].x += zv * wv[kw].x;
            acc[rr][ww].y += zv * wv[kw].y;
            acc[rr][ww].z += zv * wv[kw].z;
            acc[rr][ww].w += zv * wv[kw].w;
          }
    }
  }
  float4 bias = *(const float4*)(cb + si * 256 + o0);
  float lsum = 0.0f;
#pragma unroll
  for (int rr = 0; rr < 2; rr++)
#pragma unroll
    for (int ww = 0; ww < 4; ww++) {
      int h = h0 + rr, w = w0 + ww;
      size_t n = ((size_t)(b * 16 + h) * 16 + w) * 256 + o0;
      float4 zuv = *(float4*)&zs[(rr + 1) * 4096 + w * 256 + o0];
      float4 y;
      y.x = acc[rr][ww].x + bias.x; y.y = acc[rr][ww].y + bias.y;
      y.z = acc[rr][ww].z + bias.z; y.w = acc[rr][ww].w + bias.w;
      float4 res;
      res.x = 0.5f * (zuv.x + y.x); res.y = 0.5f * (zuv.y + y.y);
      res.z = 0.5f * (zuv.z + y.z); res.w = 0.5f * (zuv.w + y.w);
      float4 zr4 = *(float4*)(zrest + n);
      zr4.x -= res.x; zr4.y -= res.y; zr4.z -= res.z; zr4.w -= res.w;
      *(float4*)(zrest + n) = zr4;
      lsum += zr4.x * zr4.x + zr4.y * zr4.y + zr4.z * zr4.z + zr4.w * zr4.w;
    }
  red[t] = lsum;
  __syncthreads();
  for (int s = 128; s > 0; s >>= 1) { if (t < s) red[t] += red[t + s]; __syncthreads(); }
  if (t == 0) atomicAdd(out_loss, red[0] * (0.25f / (8.0f * 4194304.0f)));
}

// out NCHW = z - z_rest (z_hat_cum)
__global__ void k_out(const float* __restrict__ z, const float* __restrict__ zrest,
                      float* __restrict__ out) {
  int n = blockIdx.x, c = threadIdx.x;
  int b = n >> 8, hw = n & 255;
  size_t m = ((size_t)(b * 256 + c)) * 256 + hw;
  out[m] = z[m] - zrest[(size_t)n * 256 + c];
}

// ---------------- launch ----------------
extern "C" void kernel_launch(void* const* d_in, const int* in_sizes, int n_in,
                              void* d_out, int out_size, void* d_ws, size_t ws_size,
                              hipStream_t stream) {
  const float* z   = (const float*)d_in[0];
  const float* emb = (const float*)d_in[1];
  const float* cw  = (const float*)d_in[2];
  const float* cb  = (const float*)d_in[3];
  float* out = (float*)d_out;
  float* ws  = (float*)d_ws;

  // slim layout: 23093248 floats = 92.4 MB total
  float* z_rest = ws;                        // 4194304
  float* zu     = ws + 4194304;              // 4194304
  float* wT     = ws + 8388608;              // 4718592
  float* esq    = ws + 13107200;             // 8192
  short* A2     = (short*)(ws + 13115392);   // 16384*768 shorts = 6291456 floats
  short* B2     = (short*)(ws + 19406848);   // 8192*768 shorts  = 3145728 floats
  float* pd     = ws + 22552576;             // 16384*16 = 262144
  int*   pi     = (int*)(ws + 22814720);     // 262144
  int*   idxb   = (int*)(ws + 23076864);     // 16384

  const int pns[8] = {1, 2, 3, 4, 6, 8, 12, 16};

  k_zero<<<33, 256, 0, stream>>>(out + LOSS_OFF, 1 + NE);
  k_tr_in<<<16384, 256, 0, stream>>>(z, z_rest);
  k_prep_emb2<<<8192, 256, 0, stream>>>(emb, B2, esq);
  k_prep_w<<<4718592 / 256, 256, 0, stream>>>(cw, wT);

  for (int si = 0; si < 8; si++) {
    int pn = pns[si];
    int N = 64 * pn * pn;
    if (si < 7)
      k_down_a2<<<dim3(pn * pn, 64), 256, 0, stream>>>(z_rest, A2, pn);
    else
      k_split_a2<<<16384, 256, 0, stream>>>(z_rest, A2);
    int rb = (N + 127) / 128;
    k_dist_mfma<<<dim3(rb, 16), 256, 0, stream>>>(A2, B2, esq, pd, pi, N);
    k_red<<<(N + 255) / 256, 256, 0, stream>>>(pd, pi, idxb, out + CNT_OFF, N, 16);
    k_up<<<16384, 256, 0, stream>>>(emb, idxb, zu, pn, si == 7 ? 1 : 0);
    k_conv<<<dim3(8, 64), 256, 0, stream>>>(zu, wT, cb, z_rest, out + LOSS_OFF, si);
  }
  k_out<<<16384, 256, 0, stream>>>(z, z_rest, out);
}

// Round 6
// 3104.721 us; speedup vs baseline: 1.5738x; 1.2691x over previous
//
#include <hip/hip_runtime.h>
#include <math.h>

// Problem constants (fixed by setup_inputs)
#define NB 64
#define NC 256
#define NHW 16
#define NE 8192
#define NUMEL 4194304          // 64*256*16*16
#define LOSS_OFF 4194304
#define CNT_OFF  4194305

typedef __bf16 bf16x8 __attribute__((ext_vector_type(8)));
typedef float  f32x4  __attribute__((ext_vector_type(4)));

// ---------------- helpers ----------------
__device__ __forceinline__ float cubicw(float t) {
  // torch bicubic, a = -0.75
  t = fabsf(t);
  if (t <= 1.0f) return (1.25f * t - 2.25f) * t * t + 1.0f;
  if (t < 2.0f)  return ((-0.75f * t + 3.75f) * t - 6.0f) * t + 3.0f;
  return 0.0f;
}

__device__ __forceinline__ short f2bf(float x) {
  union { float f; unsigned int u; } v; v.f = x;
  unsigned int r = v.u + 0x7fffu + ((v.u >> 16) & 1u);  // RNE
  return (short)(r >> 16);
}
__device__ __forceinline__ float bf2f(short h) {
  union { float f; unsigned int u; } v;
  v.u = ((unsigned int)(unsigned short)h) << 16;
  return v.f;
}

// ---------------- prep kernels ----------------
// zero loss + counts region of d_out
__global__ void k_zero(float* a, int na) {
  int i = blockIdx.x * 256 + threadIdx.x;
  if (i < na) a[i] = 0.0f;
}

// z (NCHW) -> z_rest NHWC [16384][256]
__global__ void k_tr_in(const float* __restrict__ z, float* __restrict__ zrest) {
  int n = blockIdx.x, c = threadIdx.x;
  int b = n >> 8, hw = n & 255;
  zrest[(size_t)n * 256 + c] = z[((size_t)(b * 256 + c)) * 256 + hw];
}

// embedding [8192][256] -> B2 [8192][768] bf16 rows = [hi, hi, lo]; esq[8192] fp32
__global__ void k_prep_emb2(const float* __restrict__ emb, short* __restrict__ B2,
                            float* __restrict__ esq) {
  int j = blockIdx.x, t = threadIdx.x;
  float v = emb[(size_t)j * 256 + t];
  short hi = f2bf(v);
  short lo = f2bf(v - bf2f(hi));
  B2[(size_t)j * 768 + t]       = hi;
  B2[(size_t)j * 768 + 256 + t] = hi;
  B2[(size_t)j * 768 + 512 + t] = lo;
  __shared__ float red[256];
  red[t] = v * v;
  __syncthreads();
  for (int s = 128; s > 0; s >>= 1) { if (t < s) red[t] += red[t + s]; __syncthreads(); }
  if (t == 0) esq[j] = red[0];
}

// conv_w [si][o][i][kh][kw] -> wB2 [si][tap][o][768] bf16 rows = [hi, hi, lo]
__global__ void k_prep_wb(const float* __restrict__ w, short* __restrict__ wB2) {
  int m = blockIdx.x * 256 + threadIdx.x;
  if (m >= 8 * 9 * 65536) return;
  int i = m & 255, o = (m >> 8) & 255;
  int r = m >> 16;            // si*9 + tap
  int si = r / 9, tap = r % 9;
  float v = w[(((size_t)si * 256 + o) * 256 + i) * 9 + tap];
  short hi = f2bf(v);
  short lo = f2bf(v - bf2f(hi));
  size_t dst = ((size_t)r * 256 + o) * 768;
  wB2[dst + i]       = hi;
  wB2[dst + 256 + i] = hi;
  wB2[dst + 512 + i] = lo;
}

// ---------------- per-scale kernels ----------------
// area downsample: z_rest NHWC -> A2 rows [hi, lo, hi]
__global__ void k_down_a2(const float* __restrict__ zrest, short* __restrict__ A2, int pn) {
  int pq = blockIdx.x, b = blockIdx.y, c = threadIdx.x;
  int p = pq / pn, q = pq % pn;
  int sp = (p * 16) / pn, ep = ((p + 1) * 16 + pn - 1) / pn;
  int sq = (q * 16) / pn, eq = ((q + 1) * 16 + pn - 1) / pn;
  float s = 0.0f;
  for (int h = sp; h < ep; h++)
    for (int w = sq; w < eq; w++)
      s += zrest[((size_t)((b * 16 + h) * 16 + w)) * 256 + c];
  float x = s / (float)((ep - sp) * (eq - sq));
  int n = (b * pn + p) * pn + q;
  short hi = f2bf(x);
  short lo = f2bf(x - bf2f(hi));
  A2[(size_t)n * 768 + c]       = hi;
  A2[(size_t)n * 768 + 256 + c] = lo;
  A2[(size_t)n * 768 + 512 + c] = hi;
}

// identity (last scale): z_rest NHWC -> A2
__global__ void k_split_a2(const float* __restrict__ zrest, short* __restrict__ A2) {
  int n = blockIdx.x, c = threadIdx.x;
  float x = zrest[(size_t)n * 256 + c];
  short hi = f2bf(x);
  short lo = f2bf(x - bf2f(hi));
  A2[(size_t)n * 768 + c]       = hi;
  A2[(size_t)n * 768 + 256 + c] = lo;
  A2[(size_t)n * 768 + 512 + c] = hi;
}

// MFMA distance GEMM + fused argmin over 512 codes per block.
// C[n][j] = A2[n]·B2[j] (K=768 compensated bf16) ; dist = esq[j] - 2C.
// Block: 128 rows x (4 x 128 codes), 256 thr = 4 waves (2x2 of 64x64).
// Cross-wave code-half argmin combined through LDS (R5 race fix).
#define LDA 72
__global__ __launch_bounds__(256) void k_dist_mfma(
    const short* __restrict__ A2, const short* __restrict__ B2,
    const float* __restrict__ esq, float* __restrict__ pd, int* __restrict__ pi,
    int N) {
  __shared__ short As[128 * LDA];
  __shared__ short Bs[128 * LDA];
  __shared__ float sbd[2][128];
  __shared__ int   sbi[2][128];
  int t = threadIdx.x, ln = t & 63, wv = t >> 6;
  int wr = wv >> 1, wc = wv & 1;
  int n0 = blockIdx.x * 128;
  int lc = ln & 15, lq = ln >> 4;

  float best[4][4]; int bidx[4][4];
#pragma unroll
  for (int rt = 0; rt < 4; rt++)
#pragma unroll
    for (int r = 0; r < 4; r++) { best[rt][r] = 3.4e38f; bidx[rt][r] = 0; }

  for (int jt2 = 0; jt2 < 4; jt2++) {
    int jb0 = (blockIdx.y * 4 + jt2) * 128;
    f32x4 acc[4][4];
#pragma unroll
    for (int a = 0; a < 4; a++)
#pragma unroll
      for (int b = 0; b < 4; b++) acc[a][b] = (f32x4)(0.0f);

    for (int kk = 0; kk < 768; kk += 64) {
#pragma unroll
      for (int i = 0; i < 4; i++) {
        int G = i * 256 + t;          // group of 8 shorts
        int row = G >> 3, cc = G & 7;
        uint4 va = *(const uint4*)(A2 + (size_t)(n0 + row) * 768 + kk + cc * 8);
        *(uint4*)(As + row * LDA + cc * 8) = va;
        uint4 vb = *(const uint4*)(B2 + (size_t)(jb0 + row) * 768 + kk + cc * 8);
        *(uint4*)(Bs + row * LDA + cc * 8) = vb;
      }
      __syncthreads();
#pragma unroll
      for (int ks = 0; ks < 2; ks++) {
        bf16x8 fa[4], fb[4];
#pragma unroll
        for (int rt = 0; rt < 4; rt++) {
          int row = wr * 64 + rt * 16 + lc;
          fa[rt] = *(const bf16x8*)(As + row * LDA + (ks * 4 + lq) * 8);
        }
#pragma unroll
        for (int ct = 0; ct < 4; ct++) {
          int row = wc * 64 + ct * 16 + lc;
          fb[ct] = *(const bf16x8*)(Bs + row * LDA + (ks * 4 + lq) * 8);
        }
#pragma unroll
        for (int rt = 0; rt < 4; rt++)
#pragma unroll
          for (int ct = 0; ct < 4; ct++)
            acc[rt][ct] = __builtin_amdgcn_mfma_f32_16x16x32_bf16(
                fa[rt], fb[ct], acc[rt][ct], 0, 0, 0);
      }
      __syncthreads();
    }

#pragma unroll
    for (int rt = 0; rt < 4; rt++)
#pragma unroll
      for (int ct = 0; ct < 4; ct++) {
        int j = jb0 + wc * 64 + ct * 16 + lc;
        float es = esq[j];
#pragma unroll
        for (int r = 0; r < 4; r++) {
          float d = es - 2.0f * acc[rt][ct][r];
          if (d < best[rt][r]) { best[rt][r] = d; bidx[rt][r] = j; }
        }
      }
  }

#pragma unroll
  for (int rt = 0; rt < 4; rt++) {
#pragma unroll
    for (int r = 0; r < 4; r++) {
      float bd = best[rt][r]; int bi = bidx[rt][r];
#pragma unroll
      for (int off = 1; off < 16; off <<= 1) {
        float od = __shfl_xor(bd, off, 64);
        int   oi = __shfl_xor(bi, off, 64);
        if (od < bd || (od == bd && oi < bi)) { bd = od; bi = oi; }
      }
      if (lc == 0) {
        int rloc = wr * 64 + rt * 16 + lq * 4 + r;
        sbd[wc][rloc] = bd;
        sbi[wc][rloc] = bi;
      }
    }
  }
  __syncthreads();
  if (t < 128) {
    float b0 = sbd[0][t]; int i0 = sbi[0][t];
    float b1 = sbd[1][t]; int i1 = sbi[1][t];
    if (b1 < b0 || (b1 == b0 && i1 < i0)) { b0 = b1; i0 = i1; }
    int n = n0 + t;
    if (n < N) {
      pd[(size_t)n * 16 + blockIdx.y] = b0;
      pi[(size_t)n * 16 + blockIdx.y] = i0;
    }
  }
}

// reduce per-row partials over 16 code tiles -> idx, counts
__global__ void k_red(const float* __restrict__ pd, const int* __restrict__ pi,
                      int* __restrict__ idxb, float* __restrict__ counts, int N, int nct) {
  int n = blockIdx.x * 256 + threadIdx.x;
  if (n >= N) return;
  float bd = pd[(size_t)n * nct]; int bi = pi[(size_t)n * nct];
  for (int jt = 1; jt < nct; jt++) {
    float d = pd[(size_t)n * nct + jt]; int ii = pi[(size_t)n * nct + jt];
    if (d < bd || (d == bd && ii < bi)) { bd = d; bi = ii; }
  }
  idxb[n] = bi;
  atomicAdd(counts + bi, 1.0f);
}

// gather + bicubic upsample -> zu fp32 NHWC and zu2 compensated [hi,lo,hi]
__global__ void k_up(const float* __restrict__ emb, const int* __restrict__ idxb,
                     float* __restrict__ zu, short* __restrict__ zu2, int pn, int last) {
  int n = blockIdx.x, c = threadIdx.x;
  float acc;
  if (last) {
    acc = emb[(size_t)idxb[n] * 256 + c];
  } else {
    int b = n >> 8, hw = n & 255, h = hw >> 4, w = hw & 15;
    float scale = pn / 16.0f;
    float xh = (h + 0.5f) * scale - 0.5f; int fh = (int)floorf(xh);
    float xw = (w + 0.5f) * scale - 0.5f; int fw = (int)floorf(xw);
    int ph[4], pw[4]; float wh[4], wwt[4];
#pragma unroll
    for (int k = 0; k < 4; k++) {
      wh[k] = cubicw(xh - (float)(fh + k - 1));
      int pp = fh + k - 1; ph[k] = min(max(pp, 0), pn - 1);
      wwt[k] = cubicw(xw - (float)(fw + k - 1));
      pp = fw + k - 1; pw[k] = min(max(pp, 0), pn - 1);
    }
    acc = 0.0f;
#pragma unroll
    for (int kh = 0; kh < 4; kh++)
#pragma unroll
      for (int kw = 0; kw < 4; kw++) {
        int row = idxb[(n >> 8) * pn * pn + ph[kh] * pn + pw[kw]];
        acc += wh[kh] * wwt[kw] * emb[(size_t)row * 256 + c];
      }
  }
  zu[(size_t)n * 256 + c] = acc;
  short hi = f2bf(acc);
  short lo = f2bf(acc - bf2f(hi));
  zu2[(size_t)n * 768 + c]       = hi;
  zu2[(size_t)n * 768 + 256 + c] = lo;
  zu2[(size_t)n * 768 + 512 + c] = hi;
}

// 3x3 SAME conv as compensated-bf16 MFMA GEMM (K = 9 taps x 768) + fused
// bias + residual update + loss. Block: 64 px x 128 o, 256 thr = 4 waves,
// wave wv covers o-sub [wv*32, wv*32+32). Staging clones k_dist_mfma (LDA=72).
__global__ __launch_bounds__(256) void k_conv_mfma(
    const short* __restrict__ zu2, const short* __restrict__ wB2,
    const float* __restrict__ cb, const float* __restrict__ zu,
    float* __restrict__ zrest, float* __restrict__ out_loss, int si) {
  __shared__ short As[64 * LDA];
  __shared__ short Bs[128 * LDA];
  __shared__ float red[256];
  int t = threadIdx.x, ln = t & 63, wv = t >> 6;
  int lc = ln & 15, lq = ln >> 4;
  int b = blockIdx.x >> 2, h0 = (blockIdx.x & 3) * 4;
  int o0 = blockIdx.y * 128;

  f32x4 acc[4][2];
#pragma unroll
  for (int rt = 0; rt < 4; rt++)
#pragma unroll
    for (int ct = 0; ct < 2; ct++) acc[rt][ct] = (f32x4)(0.0f);

  for (int kh = 0; kh < 3; kh++) {
    for (int kw = 0; kw < 3; kw++) {
      int tap = kh * 3 + kw;
      const short* bbase = wB2 + (((size_t)si * 9 + tap) * 256 + o0) * 768;
      // per-thread A-source (shifted rows, border zero), hoisted out of kc loop
      const short* asrc[2]; bool aok[2]; int adst[2];
#pragma unroll
      for (int i = 0; i < 2; i++) {
        int G = i * 256 + t, row = G >> 3, cc = G & 7;
        int hs = h0 + (row >> 4) + kh - 1, ws = (row & 15) + kw - 1;
        aok[i] = (hs >= 0 && hs < 16 && ws >= 0 && ws < 16);
        int nsrc = aok[i] ? (b * 256 + hs * 16 + ws) : 0;
        asrc[i] = zu2 + (size_t)nsrc * 768 + cc * 8;
        adst[i] = row * LDA + cc * 8;
      }
      for (int kc = 0; kc < 12; kc++) {
#pragma unroll
        for (int i = 0; i < 2; i++) {
          uint4 v = make_uint4(0u, 0u, 0u, 0u);
          if (aok[i]) v = *(const uint4*)(asrc[i] + kc * 64);
          *(uint4*)(As + adst[i]) = v;
        }
#pragma unroll
        for (int i = 0; i < 4; i++) {
          int G = i * 256 + t, row = G >> 3, cc = G & 7;
          uint4 v = *(const uint4*)(bbase + (size_t)row * 768 + kc * 64 + cc * 8);
          *(uint4*)(Bs + row * LDA + cc * 8) = v;
        }
        __syncthreads();
#pragma unroll
        for (int ks = 0; ks < 2; ks++) {
          bf16x8 fa[4], fb[2];
#pragma unroll
          for (int rt = 0; rt < 4; rt++)
            fa[rt] = *(const bf16x8*)(As + (rt * 16 + lc) * LDA + (ks * 4 + lq) * 8);
#pragma unroll
          for (int ct = 0; ct < 2; ct++)
            fb[ct] = *(const bf16x8*)(Bs + (wv * 32 + ct * 16 + lc) * LDA + (ks * 4 + lq) * 8);
#pragma unroll
          for (int rt = 0; rt < 4; rt++)
#pragma unroll
            for (int ct = 0; ct < 2; ct++)
              acc[rt][ct] = __builtin_amdgcn_mfma_f32_16x16x32_bf16(
                  fa[rt], fb[ct], acc[rt][ct], 0, 0, 0);
        }
        __syncthreads();
      }
    }
  }

  // epilogue: y = acc + bias; res = 0.5*(zu+y); zrest -= res; loss += zrest^2
  float lsum = 0.0f;
#pragma unroll
  for (int ct = 0; ct < 2; ct++) {
    int o = o0 + wv * 32 + ct * 16 + lc;
    float bias = cb[si * 256 + o];
#pragma unroll
    for (int rt = 0; rt < 4; rt++) {
#pragma unroll
      for (int r = 0; r < 4; r++) {
        int px = rt * 16 + lq * 4 + r;
        int n = b * 256 + (h0 + (px >> 4)) * 16 + (px & 15);
        size_t m = (size_t)n * 256 + o;
        float y = acc[rt][ct][r] + bias;
        float res = 0.5f * (zu[m] + y);
        float nv = zrest[m] - res;
        zrest[m] = nv;
        lsum += nv * nv;
      }
    }
  }
  red[t] = lsum;
  __syncthreads();
  for (int s = 128; s > 0; s >>= 1) { if (t < s) red[t] += red[t + s]; __syncthreads(); }
  if (t == 0) atomicAdd(out_loss, red[0] * (0.25f / (8.0f * 4194304.0f)));
}

// out NCHW = z - z_rest (z_hat_cum)
__global__ void k_out(const float* __restrict__ z, const float* __restrict__ zrest,
                      float* __restrict__ out) {
  int n = blockIdx.x, c = threadIdx.x;
  int b = n >> 8, hw = n & 255;
  size_t m = ((size_t)(b * 256 + c)) * 256 + hw;
  out[m] = z[m] - zrest[(size_t)n * 256 + c];
}

// ---------------- launch ----------------
extern "C" void kernel_launch(void* const* d_in, const int* in_sizes, int n_in,
                              void* d_out, int out_size, void* d_ws, size_t ws_size,
                              hipStream_t stream) {
  const float* z   = (const float*)d_in[0];
  const float* emb = (const float*)d_in[1];
  const float* cw  = (const float*)d_in[2];
  const float* cb  = (const float*)d_in[3];
  float* out = (float*)d_out;
  float* ws  = (float*)d_ws;

  // layout: 25,452,544 floats = 101.8 MB (R1 proved ~112 MB works)
  float* z_rest = ws;                        // 4,194,304
  float* zu     = ws + 4194304;              // 4,194,304
  float* esq    = ws + 8388608;              // 8,192
  short* A2     = (short*)(ws + 8396800);    // 16384*768 shorts = 6,291,456 floats
  short* zu2    = A2;                        // reuses A2 (free after dist)
  short* B2     = (short*)(ws + 14688256);   // 8192*768 shorts  = 3,145,728 floats
  short* wB2    = (short*)(ws + 17833984);   // 8*9*256*768 shorts = 7,077,888 floats
  float* pd     = ws + 24911872;             // 262,144
  int*   pi     = (int*)(ws + 25174016);     // 262,144
  int*   idxb   = (int*)(ws + 25436160);     // 16,384

  const int pns[8] = {1, 2, 3, 4, 6, 8, 12, 16};

  k_zero<<<33, 256, 0, stream>>>(out + LOSS_OFF, 1 + NE);
  k_tr_in<<<16384, 256, 0, stream>>>(z, z_rest);
  k_prep_emb2<<<8192, 256, 0, stream>>>(emb, B2, esq);
  k_prep_wb<<<18432, 256, 0, stream>>>(cw, wB2);

  for (int si = 0; si < 8; si++) {
    int pn = pns[si];
    int N = 64 * pn * pn;
    if (si < 7)
      k_down_a2<<<dim3(pn * pn, 64), 256, 0, stream>>>(z_rest, A2, pn);
    else
      k_split_a2<<<16384, 256, 0, stream>>>(z_rest, A2);
    int rb = (N + 127) / 128;
    k_dist_mfma<<<dim3(rb, 16), 256, 0, stream>>>(A2, B2, esq, pd, pi, N);
    k_red<<<(N + 255) / 256, 256, 0, stream>>>(pd, pi, idxb, out + CNT_OFF, N, 16);
    k_up<<<16384, 256, 0, stream>>>(emb, idxb, zu, zu2, pn, si == 7 ? 1 : 0);
    k_conv_mfma<<<dim3(256, 2), 256, 0, stream>>>(zu2, wB2, cb, zu, z_rest,
                                                  out + LOSS_OFF, si);
  }
  k_out<<<16384, 256, 0, stream>>>(z, z_rest, out);
}

// Round 7
// 2980.768 us; speedup vs baseline: 1.6393x; 1.0416x over previous
//
#include <hip/hip_runtime.h>
#include <math.h>

// Problem constants (fixed by setup_inputs)
#define NB 64
#define NC 256
#define NHW 16
#define NE 8192
#define NUMEL 4194304          // 64*256*16*16
#define LOSS_OFF 4194304
#define CNT_OFF  4194305

typedef __bf16 bf16x8 __attribute__((ext_vector_type(8)));
typedef float  f32x4  __attribute__((ext_vector_type(4)));

#define GLOAD_LDS(gptr, lptr) \
  __builtin_amdgcn_global_load_lds( \
      (const __attribute__((address_space(1))) unsigned int*)(gptr), \
      (__attribute__((address_space(3))) unsigned int*)(lptr), 16, 0, 0)

// ---------------- helpers ----------------
__device__ __forceinline__ float cubicw(float t) {
  // torch bicubic, a = -0.75
  t = fabsf(t);
  if (t <= 1.0f) return (1.25f * t - 2.25f) * t * t + 1.0f;
  if (t < 2.0f)  return ((-0.75f * t + 3.75f) * t - 6.0f) * t + 3.0f;
  return 0.0f;
}

__device__ __forceinline__ short f2bf(float x) {
  union { float f; unsigned int u; } v; v.f = x;
  unsigned int r = v.u + 0x7fffu + ((v.u >> 16) & 1u);  // RNE
  return (short)(r >> 16);
}
__device__ __forceinline__ float bf2f(short h) {
  union { float f; unsigned int u; } v;
  v.u = ((unsigned int)(unsigned short)h) << 16;
  return v.f;
}

// ---------------- prep kernels ----------------
// zero loss + counts region of d_out
__global__ void k_zero(float* a, int na) {
  int i = blockIdx.x * 256 + threadIdx.x;
  if (i < na) a[i] = 0.0f;
}

// z (NCHW) -> z_rest NHWC [16384][256]
__global__ void k_tr_in(const float* __restrict__ z, float* __restrict__ zrest) {
  int n = blockIdx.x, c = threadIdx.x;
  int b = n >> 8, hw = n & 255;
  zrest[(size_t)n * 256 + c] = z[((size_t)(b * 256 + c)) * 256 + hw];
}

// embedding [8192][256] -> B2 [8192][768] bf16 rows = [hi, hi, lo]; esq[8192] fp32
__global__ void k_prep_emb2(const float* __restrict__ emb, short* __restrict__ B2,
                            float* __restrict__ esq) {
  int j = blockIdx.x, t = threadIdx.x;
  float v = emb[(size_t)j * 256 + t];
  short hi = f2bf(v);
  short lo = f2bf(v - bf2f(hi));
  B2[(size_t)j * 768 + t]       = hi;
  B2[(size_t)j * 768 + 256 + t] = hi;
  B2[(size_t)j * 768 + 512 + t] = lo;
  __shared__ float red[256];
  red[t] = v * v;
  __syncthreads();
  for (int s = 128; s > 0; s >>= 1) { if (t < s) red[t] += red[t + s]; __syncthreads(); }
  if (t == 0) esq[j] = red[0];
}

// conv_w [si][o][i][kh][kw] -> wB2 [si][tap][o][768] bf16 rows = [hi, hi, lo]
__global__ void k_prep_wb(const float* __restrict__ w, short* __restrict__ wB2) {
  int m = blockIdx.x * 256 + threadIdx.x;
  if (m >= 8 * 9 * 65536) return;
  int i = m & 255, o = (m >> 8) & 255;
  int r = m >> 16;            // si*9 + tap
  int si = r / 9, tap = r % 9;
  float v = w[(((size_t)si * 256 + o) * 256 + i) * 9 + tap];
  short hi = f2bf(v);
  short lo = f2bf(v - bf2f(hi));
  size_t dst = ((size_t)r * 256 + o) * 768;
  wB2[dst + i]       = hi;
  wB2[dst + 256 + i] = hi;
  wB2[dst + 512 + i] = lo;
}

// ---------------- per-scale kernels ----------------
// area downsample: z_rest NHWC -> A2 rows [hi, lo, hi]
__global__ void k_down_a2(const float* __restrict__ zrest, short* __restrict__ A2, int pn) {
  int pq = blockIdx.x, b = blockIdx.y, c = threadIdx.x;
  int p = pq / pn, q = pq % pn;
  int sp = (p * 16) / pn, ep = ((p + 1) * 16 + pn - 1) / pn;
  int sq = (q * 16) / pn, eq = ((q + 1) * 16 + pn - 1) / pn;
  float s = 0.0f;
  for (int h = sp; h < ep; h++)
    for (int w = sq; w < eq; w++)
      s += zrest[((size_t)((b * 16 + h) * 16 + w)) * 256 + c];
  float x = s / (float)((ep - sp) * (eq - sq));
  int n = (b * pn + p) * pn + q;
  short hi = f2bf(x);
  short lo = f2bf(x - bf2f(hi));
  A2[(size_t)n * 768 + c]       = hi;
  A2[(size_t)n * 768 + 256 + c] = lo;
  A2[(size_t)n * 768 + 512 + c] = hi;
}

// identity (last scale): z_rest NHWC -> A2
__global__ void k_split_a2(const float* __restrict__ zrest, short* __restrict__ A2) {
  int n = blockIdx.x, c = threadIdx.x;
  float x = zrest[(size_t)n * 256 + c];
  short hi = f2bf(x);
  short lo = f2bf(x - bf2f(hi));
  A2[(size_t)n * 768 + c]       = hi;
  A2[(size_t)n * 768 + 256 + c] = lo;
  A2[(size_t)n * 768 + 512 + c] = hi;
}

// MFMA distance GEMM + fused argmin over 512 codes per block.
// C[n][j] = A2[n]·B2[j] (K=768 compensated bf16) ; dist = esq[j] - 2C.
// Block: 128 rows x (4 x 128 codes), 256 thr = 4 waves (2x2 of 64x64).
// Cross-wave code-half argmin combined through LDS (R5 race fix).
// R7: staging via global_load_lds width=16 with XOR-chunk swizzle (swizzle on
// the GLOBAL index; LDS side linear per the wave-uniform-base constraint).
__global__ __launch_bounds__(256) void k_dist_mfma(
    const short* __restrict__ A2, const short* __restrict__ B2,
    const float* __restrict__ esq, float* __restrict__ pd, int* __restrict__ pi,
    int N) {
  __shared__ short As[128 * 64];
  __shared__ short Bs[128 * 64];
  __shared__ float sbd[2][128];
  __shared__ int   sbi[2][128];
  int t = threadIdx.x, ln = t & 63, wv = t >> 6;
  int wr = wv >> 1, wc = wv & 1;
  int n0 = blockIdx.x * 128;
  int lc = ln & 15, lq = ln >> 4;

  float best[4][4]; int bidx[4][4];
#pragma unroll
  for (int rt = 0; rt < 4; rt++)
#pragma unroll
    for (int r = 0; r < 4; r++) { best[rt][r] = 3.4e38f; bidx[rt][r] = 0; }

  for (int jt2 = 0; jt2 < 4; jt2++) {
    int jb0 = (blockIdx.y * 4 + jt2) * 128;
    f32x4 acc[4][4];
#pragma unroll
    for (int a = 0; a < 4; a++)
#pragma unroll
      for (int b = 0; b < 4; b++) acc[a][b] = (f32x4)(0.0f);

    for (int kk = 0; kk < 768; kk += 64) {
#pragma unroll
      for (int i = 0; i < 4; i++) {
        int Lb = i * 256 + wv * 64;       // wave-uniform chunk base (8-short units)
        int L = Lb + ln;
        int row = L >> 3, cc = L & 7;
        int gc = cc ^ (row & 7);          // XOR swizzle on the global side
        GLOAD_LDS(A2 + (size_t)(n0 + row) * 768 + kk + gc * 8, As + Lb * 8);
        GLOAD_LDS(B2 + (size_t)(jb0 + row) * 768 + kk + gc * 8, Bs + Lb * 8);
      }
      __syncthreads();
#pragma unroll
      for (int ks = 0; ks < 2; ks++) {
        bf16x8 fa[4], fb[4];
#pragma unroll
        for (int rt = 0; rt < 4; rt++) {
          int row = wr * 64 + rt * 16 + lc;
          int cc = (ks * 4 + lq) ^ (row & 7);
          fa[rt] = *(const bf16x8*)(As + row * 64 + cc * 8);
        }
#pragma unroll
        for (int ct = 0; ct < 4; ct++) {
          int row = wc * 64 + ct * 16 + lc;
          int cc = (ks * 4 + lq) ^ (row & 7);
          fb[ct] = *(const bf16x8*)(Bs + row * 64 + cc * 8);
        }
#pragma unroll
        for (int rt = 0; rt < 4; rt++)
#pragma unroll
          for (int ct = 0; ct < 4; ct++)
            acc[rt][ct] = __builtin_amdgcn_mfma_f32_16x16x32_bf16(
                fa[rt], fb[ct], acc[rt][ct], 0, 0, 0);
      }
      __syncthreads();
    }

#pragma unroll
    for (int rt = 0; rt < 4; rt++)
#pragma unroll
      for (int ct = 0; ct < 4; ct++) {
        int j = jb0 + wc * 64 + ct * 16 + lc;
        float es = esq[j];
#pragma unroll
        for (int r = 0; r < 4; r++) {
          float d = es - 2.0f * acc[rt][ct][r];
          if (d < best[rt][r]) { best[rt][r] = d; bidx[rt][r] = j; }
        }
      }
  }

#pragma unroll
  for (int rt = 0; rt < 4; rt++) {
#pragma unroll
    for (int r = 0; r < 4; r++) {
      float bd = best[rt][r]; int bi = bidx[rt][r];
#pragma unroll
      for (int off = 1; off < 16; off <<= 1) {
        float od = __shfl_xor(bd, off, 64);
        int   oi = __shfl_xor(bi, off, 64);
        if (od < bd || (od == bd && oi < bi)) { bd = od; bi = oi; }
      }
      if (lc == 0) {
        int rloc = wr * 64 + rt * 16 + lq * 4 + r;
        sbd[wc][rloc] = bd;
        sbi[wc][rloc] = bi;
      }
    }
  }
  __syncthreads();
  if (t < 128) {
    float b0 = sbd[0][t]; int i0 = sbi[0][t];
    float b1 = sbd[1][t]; int i1 = sbi[1][t];
    if (b1 < b0 || (b1 == b0 && i1 < i0)) { b0 = b1; i0 = i1; }
    int n = n0 + t;
    if (n < N) {
      pd[(size_t)n * 16 + blockIdx.y] = b0;
      pi[(size_t)n * 16 + blockIdx.y] = i0;
    }
  }
}

// reduce per-row partials over 16 code tiles -> idx, counts
__global__ void k_red(const float* __restrict__ pd, const int* __restrict__ pi,
                      int* __restrict__ idxb, float* __restrict__ counts, int N, int nct) {
  int n = blockIdx.x * 256 + threadIdx.x;
  if (n >= N) return;
  float bd = pd[(size_t)n * nct]; int bi = pi[(size_t)n * nct];
  for (int jt = 1; jt < nct; jt++) {
    float d = pd[(size_t)n * nct + jt]; int ii = pi[(size_t)n * nct + jt];
    if (d < bd || (d == bd && ii < bi)) { bd = d; bi = ii; }
  }
  idxb[n] = bi;
  atomicAdd(counts + bi, 1.0f);
}

// gather + bicubic upsample -> zu fp32 NHWC and zu2 compensated [hi,lo,hi]
__global__ void k_up(const float* __restrict__ emb, const int* __restrict__ idxb,
                     float* __restrict__ zu, short* __restrict__ zu2, int pn, int last) {
  int n = blockIdx.x, c = threadIdx.x;
  float acc;
  if (last) {
    acc = emb[(size_t)idxb[n] * 256 + c];
  } else {
    int b = n >> 8, hw = n & 255, h = hw >> 4, w = hw & 15;
    float scale = pn / 16.0f;
    float xh = (h + 0.5f) * scale - 0.5f; int fh = (int)floorf(xh);
    float xw = (w + 0.5f) * scale - 0.5f; int fw = (int)floorf(xw);
    int ph[4], pw[4]; float wh[4], wwt[4];
#pragma unroll
    for (int k = 0; k < 4; k++) {
      wh[k] = cubicw(xh - (float)(fh + k - 1));
      int pp = fh + k - 1; ph[k] = min(max(pp, 0), pn - 1);
      wwt[k] = cubicw(xw - (float)(fw + k - 1));
      pp = fw + k - 1; pw[k] = min(max(pp, 0), pn - 1);
    }
    acc = 0.0f;
#pragma unroll
    for (int kh = 0; kh < 4; kh++)
#pragma unroll
      for (int kw = 0; kw < 4; kw++) {
        int row = idxb[(n >> 8) * pn * pn + ph[kh] * pn + pw[kw]];
        acc += wh[kh] * wwt[kw] * emb[(size_t)row * 256 + c];
      }
  }
  zu[(size_t)n * 256 + c] = acc;
  short hi = f2bf(acc);
  short lo = f2bf(acc - bf2f(hi));
  zu2[(size_t)n * 768 + c]       = hi;
  zu2[(size_t)n * 768 + 256 + c] = lo;
  zu2[(size_t)n * 768 + 512 + c] = hi;
}

// 3x3 SAME conv as compensated-bf16 MFMA GEMM (K = 9 taps x 768) + fused
// bias + residual update + loss. Block: 64 px x 128 o, 256 thr = 4 waves,
// wave wv covers o-sub [wv*32, wv*32+32).
// R7: weight tile Bs via global_load_lds + XOR swizzle; As stays manual
// (needs per-lane border zeroing) with LDA=72 pad.
#define LDA 72
__global__ __launch_bounds__(256) void k_conv_mfma(
    const short* __restrict__ zu2, const short* __restrict__ wB2,
    const float* __restrict__ cb, const float* __restrict__ zu,
    float* __restrict__ zrest, float* __restrict__ out_loss, int si) {
  __shared__ short As[64 * LDA];
  __shared__ short Bs[128 * 64];
  __shared__ float red[256];
  int t = threadIdx.x, ln = t & 63, wv = t >> 6;
  int lc = ln & 15, lq = ln >> 4;
  int b = blockIdx.x >> 2, h0 = (blockIdx.x & 3) * 4;
  int o0 = blockIdx.y * 128;

  f32x4 acc[4][2];
#pragma unroll
  for (int rt = 0; rt < 4; rt++)
#pragma unroll
    for (int ct = 0; ct < 2; ct++) acc[rt][ct] = (f32x4)(0.0f);

  for (int kh = 0; kh < 3; kh++) {
    for (int kw = 0; kw < 3; kw++) {
      int tap = kh * 3 + kw;
      const short* bbase = wB2 + (((size_t)si * 9 + tap) * 256 + o0) * 768;
      // per-thread A-source (shifted rows, border zero), hoisted out of kc loop
      const short* asrc[2]; bool aok[2]; int adst[2];
#pragma unroll
      for (int i = 0; i < 2; i++) {
        int G = i * 256 + t, row = G >> 3, cc = G & 7;
        int hs = h0 + (row >> 4) + kh - 1, ws = (row & 15) + kw - 1;
        aok[i] = (hs >= 0 && hs < 16 && ws >= 0 && ws < 16);
        int nsrc = aok[i] ? (b * 256 + hs * 16 + ws) : 0;
        asrc[i] = zu2 + (size_t)nsrc * 768 + cc * 8;
        adst[i] = row * LDA + cc * 8;
      }
      for (int kc = 0; kc < 12; kc++) {
#pragma unroll
        for (int i = 0; i < 2; i++) {
          uint4 v = make_uint4(0u, 0u, 0u, 0u);
          if (aok[i]) v = *(const uint4*)(asrc[i] + kc * 64);
          *(uint4*)(As + adst[i]) = v;
        }
#pragma unroll
        for (int i = 0; i < 4; i++) {
          int Lb = i * 256 + wv * 64;
          int L = Lb + ln;
          int row = L >> 3, cc = L & 7;
          int gc = cc ^ (row & 7);
          GLOAD_LDS(bbase + (size_t)row * 768 + kc * 64 + gc * 8, Bs + Lb * 8);
        }
        __syncthreads();
#pragma unroll
        for (int ks = 0; ks < 2; ks++) {
          bf16x8 fa[4], fb[2];
#pragma unroll
          for (int rt = 0; rt < 4; rt++)
            fa[rt] = *(const bf16x8*)(As + (rt * 16 + lc) * LDA + (ks * 4 + lq) * 8);
#pragma unroll
          for (int ct = 0; ct < 2; ct++) {
            int row = wv * 32 + ct * 16 + lc;
            int cc = (ks * 4 + lq) ^ (row & 7);
            fb[ct] = *(const bf16x8*)(Bs + row * 64 + cc * 8);
          }
#pragma unroll
          for (int rt = 0; rt < 4; rt++)
#pragma unroll
            for (int ct = 0; ct < 2; ct++)
              acc[rt][ct] = __builtin_amdgcn_mfma_f32_16x16x32_bf16(
                  fa[rt], fb[ct], acc[rt][ct], 0, 0, 0);
        }
        __syncthreads();
      }
    }
  }

  // epilogue: y = acc + bias; res = 0.5*(zu+y); zrest -= res; loss += zrest^2
  float lsum = 0.0f;
#pragma unroll
  for (int ct = 0; ct < 2; ct++) {
    int o = o0 + wv * 32 + ct * 16 + lc;
    float bias = cb[si * 256 + o];
#pragma unroll
    for (int rt = 0; rt < 4; rt++) {
#pragma unroll
      for (int r = 0; r < 4; r++) {
        int px = rt * 16 + lq * 4 + r;
        int n = b * 256 + (h0 + (px >> 4)) * 16 + (px & 15);
        size_t m = (size_t)n * 256 + o;
        float y = acc[rt][ct][r] + bias;
        float res = 0.5f * (zu[m] + y);
        float nv = zrest[m] - res;
        zrest[m] = nv;
        lsum += nv * nv;
      }
    }
  }
  red[t] = lsum;
  __syncthreads();
  for (int s = 128; s > 0; s >>= 1) { if (t < s) red[t] += red[t + s]; __syncthreads(); }
  if (t == 0) atomicAdd(out_loss, red[0] * (0.25f / (8.0f * 4194304.0f)));
}

// out NCHW = z - z_rest (z_hat_cum)
__global__ void k_out(const float* __restrict__ z, const float* __restrict__ zrest,
                      float* __restrict__ out) {
  int n = blockIdx.x, c = threadIdx.x;
  int b = n >> 8, hw = n & 255;
  size_t m = ((size_t)(b * 256 + c)) * 256 + hw;
  out[m] = z[m] - zrest[(size_t)n * 256 + c];
}

// ---------------- launch ----------------
extern "C" void kernel_launch(void* const* d_in, const int* in_sizes, int n_in,
                              void* d_out, int out_size, void* d_ws, size_t ws_size,
                              hipStream_t stream) {
  const float* z   = (const float*)d_in[0];
  const float* emb = (const float*)d_in[1];
  const float* cw  = (const float*)d_in[2];
  const float* cb  = (const float*)d_in[3];
  float* out = (float*)d_out;
  float* ws  = (float*)d_ws;

  // layout: 25,452,544 floats = 101.8 MB
  float* z_rest = ws;                        // 4,194,304
  float* zu     = ws + 4194304;              // 4,194,304
  float* esq    = ws + 8388608;              // 8,192
  short* A2     = (short*)(ws + 8396800);    // 16384*768 shorts = 6,291,456 floats
  short* zu2    = A2;                        // reuses A2 (free after dist)
  short* B2     = (short*)(ws + 14688256);   // 8192*768 shorts  = 3,145,728 floats
  short* wB2    = (short*)(ws + 17833984);   // 8*9*256*768 shorts = 7,077,888 floats
  float* pd     = ws + 24911872;             // 262,144
  int*   pi     = (int*)(ws + 25174016);     // 262,144
  int*   idxb   = (int*)(ws + 25436160);     // 16,384

  const int pns[8] = {1, 2, 3, 4, 6, 8, 12, 16};

  k_zero<<<33, 256, 0, stream>>>(out + LOSS_OFF, 1 + NE);
  k_tr_in<<<16384, 256, 0, stream>>>(z, z_rest);
  k_prep_emb2<<<8192, 256, 0, stream>>>(emb, B2, esq);
  k_prep_wb<<<18432, 256, 0, stream>>>(cw, wB2);

  for (int si = 0; si < 8; si++) {
    int pn = pns[si];
    int N = 64 * pn * pn;
    if (si < 7)
      k_down_a2<<<dim3(pn * pn, 64), 256, 0, stream>>>(z_rest, A2, pn);
    else
      k_split_a2<<<16384, 256, 0, stream>>>(z_rest, A2);
    int rb = (N + 127) / 128;
    k_dist_mfma<<<dim3(rb, 16), 256, 0, stream>>>(A2, B2, esq, pd, pi, N);
    k_red<<<(N + 255) / 256, 256, 0, stream>>>(pd, pi, idxb, out + CNT_OFF, N, 16);
    k_up<<<16384, 256, 0, stream>>>(emb, idxb, zu, zu2, pn, si == 7 ? 1 : 0);
    k_conv_mfma<<<dim3(256, 2), 256, 0, stream>>>(zu2, wB2, cb, zu, z_rest,
                                                  out + LOSS_OFF, si);
  }
  k_out<<<16384, 256, 0, stream>>>(z, z_rest, out);
}

// Round 9
// 2730.995 us; speedup vs baseline: 1.7892x; 1.0915x over previous
//
#include <hip/hip_runtime.h>
#include <math.h>

// Problem constants (fixed by setup_inputs)
#define NB 64
#define NC 256
#define NHW 16
#define NE 8192
#define NUMEL 4194304          // 64*256*16*16
#define LOSS_OFF 4194304
#define CNT_OFF  4194305

typedef __bf16 bf16x8 __attribute__((ext_vector_type(8)));
typedef float  f32x4  __attribute__((ext_vector_type(4)));

#define GLOAD_LDS(gptr, lptr) \
  __builtin_amdgcn_global_load_lds( \
      (const __attribute__((address_space(1))) unsigned int*)(gptr), \
      (__attribute__((address_space(3))) unsigned int*)(lptr), 16, 0, 0)

// ---------------- helpers ----------------
__device__ __forceinline__ float cubicw(float t) {
  // torch bicubic, a = -0.75
  t = fabsf(t);
  if (t <= 1.0f) return (1.25f * t - 2.25f) * t * t + 1.0f;
  if (t < 2.0f)  return ((-0.75f * t + 3.75f) * t - 6.0f) * t + 3.0f;
  return 0.0f;
}

__device__ __forceinline__ short f2bf(float x) {
  union { float f; unsigned int u; } v; v.f = x;
  unsigned int r = v.u + 0x7fffu + ((v.u >> 16) & 1u);  // RNE
  return (short)(r >> 16);
}
__device__ __forceinline__ float bf2f(short h) {
  union { float f; unsigned int u; } v;
  v.u = ((unsigned int)(unsigned short)h) << 16;
  return v.f;
}

// ---------------- prep kernels ----------------
// zero loss + counts region of d_out
__global__ void k_zero(float* a, int na) {
  int i = blockIdx.x * 256 + threadIdx.x;
  if (i < na) a[i] = 0.0f;
}

// z (NCHW) -> z_rest NHWC [16384][256]
__global__ void k_tr_in(const float* __restrict__ z, float* __restrict__ zrest) {
  int n = blockIdx.x, c = threadIdx.x;
  int b = n >> 8, hw = n & 255;
  zrest[(size_t)n * 256 + c] = z[((size_t)(b * 256 + c)) * 256 + hw];
}

// embedding [8192][256] -> B2 [8192][768] bf16 rows = [hi, hi, lo]; esq[8192] fp32
__global__ void k_prep_emb2(const float* __restrict__ emb, short* __restrict__ B2,
                            float* __restrict__ esq) {
  int j = blockIdx.x, t = threadIdx.x;
  float v = emb[(size_t)j * 256 + t];
  short hi = f2bf(v);
  short lo = f2bf(v - bf2f(hi));
  B2[(size_t)j * 768 + t]       = hi;
  B2[(size_t)j * 768 + 256 + t] = hi;
  B2[(size_t)j * 768 + 512 + t] = lo;
  __shared__ float red[256];
  red[t] = v * v;
  __syncthreads();
  for (int s = 128; s > 0; s >>= 1) { if (t < s) red[t] += red[t + s]; __syncthreads(); }
  if (t == 0) esq[j] = red[0];
}

// conv_w [si][o][i][kh][kw] -> wB2 [si][tap][o][768] bf16 rows = [hi, hi, lo]
__global__ void k_prep_wb(const float* __restrict__ w, short* __restrict__ wB2) {
  int m = blockIdx.x * 256 + threadIdx.x;
  if (m >= 8 * 9 * 65536) return;
  int i = m & 255, o = (m >> 8) & 255;
  int r = m >> 16;            // si*9 + tap
  int si = r / 9, tap = r % 9;
  float v = w[(((size_t)si * 256 + o) * 256 + i) * 9 + tap];
  short hi = f2bf(v);
  short lo = f2bf(v - bf2f(hi));
  size_t dst = ((size_t)r * 256 + o) * 768;
  wB2[dst + i]       = hi;
  wB2[dst + 256 + i] = hi;
  wB2[dst + 512 + i] = lo;
}

// ---------------- per-scale kernels ----------------
// area downsample: z_rest NHWC -> A2 rows [hi, lo, hi]
__global__ void k_down_a2(const float* __restrict__ zrest, short* __restrict__ A2, int pn) {
  int pq = blockIdx.x, b = blockIdx.y, c = threadIdx.x;
  int p = pq / pn, q = pq % pn;
  int sp = (p * 16) / pn, ep = ((p + 1) * 16 + pn - 1) / pn;
  int sq = (q * 16) / pn, eq = ((q + 1) * 16 + pn - 1) / pn;
  float s = 0.0f;
  for (int h = sp; h < ep; h++)
    for (int w = sq; w < eq; w++)
      s += zrest[((size_t)((b * 16 + h) * 16 + w)) * 256 + c];
  float x = s / (float)((ep - sp) * (eq - sq));
  int n = (b * pn + p) * pn + q;
  short hi = f2bf(x);
  short lo = f2bf(x - bf2f(hi));
  A2[(size_t)n * 768 + c]       = hi;
  A2[(size_t)n * 768 + 256 + c] = lo;
  A2[(size_t)n * 768 + 512 + c] = hi;
}

// identity (last scale): z_rest NHWC -> A2
__global__ void k_split_a2(const float* __restrict__ zrest, short* __restrict__ A2) {
  int n = blockIdx.x, c = threadIdx.x;
  float x = zrest[(size_t)n * 256 + c];
  short hi = f2bf(x);
  short lo = f2bf(x - bf2f(hi));
  A2[(size_t)n * 768 + c]       = hi;
  A2[(size_t)n * 768 + 256 + c] = lo;
  A2[(size_t)n * 768 + 512 + c] = hi;
}

// MFMA distance GEMM + fused argmin, R9 structure:
// block = 128 rows x 256 codes, K outer (768, 3-term compensated), both
// 128-code subtiles resident in acc. A staged ONCE per K-chunk (was 4x),
// 64 MFMA/wave per barrier-pair (was 32). Waves 2x2; wave covers
// 64 rows x 128 codes. Cross-wave code-half argmin combined via LDS.
__global__ __launch_bounds__(256) void k_dist_mfma(
    const short* __restrict__ A2, const short* __restrict__ B2,
    const float* __restrict__ esq, float* __restrict__ pd, int* __restrict__ pi,
    int N) {
  __shared__ short As[128 * 64];    // 16 KB
  __shared__ short Bs[256 * 64];    // 32 KB
  __shared__ float sbd[2][128];
  __shared__ int   sbi[2][128];
  int t = threadIdx.x, ln = t & 63, wv = t >> 6;
  int wr = wv >> 1, wc = wv & 1;
  int n0 = blockIdx.x * 128;
  int jb0 = blockIdx.y * 256;
  int lc = ln & 15, lq = ln >> 4;

  f32x4 acc[4][8];
#pragma unroll
  for (int rt = 0; rt < 4; rt++)
#pragma unroll
    for (int ct = 0; ct < 8; ct++) acc[rt][ct] = (f32x4)(0.0f);

  for (int kk = 0; kk < 768; kk += 64) {
#pragma unroll
    for (int i = 0; i < 4; i++) {      // A: 128 rows x 64 shorts
      int Lb = i * 256 + wv * 64;      // wave-uniform base (8-short units)
      int L = Lb + ln;
      int row = L >> 3, cc = L & 7;
      int gc = cc ^ (row & 7);         // XOR swizzle on the global side
      GLOAD_LDS(A2 + (size_t)(n0 + row) * 768 + kk + gc * 8, As + Lb * 8);
    }
#pragma unroll
    for (int i = 0; i < 8; i++) {      // B: 256 rows x 64 shorts
      int Lb = i * 256 + wv * 64;
      int L = Lb + ln;
      int row = L >> 3, cc = L & 7;
      int gc = cc ^ (row & 7);
      GLOAD_LDS(B2 + (size_t)(jb0 + row) * 768 + kk + gc * 8, Bs + Lb * 8);
    }
    __syncthreads();
#pragma unroll
    for (int ks = 0; ks < 2; ks++) {
      bf16x8 fa[4], fb[8];
#pragma unroll
      for (int rt = 0; rt < 4; rt++) {
        int row = wr * 64 + rt * 16 + lc;
        int cc = (ks * 4 + lq) ^ (row & 7);
        fa[rt] = *(const bf16x8*)(As + row * 64 + cc * 8);
      }
#pragma unroll
      for (int ct = 0; ct < 8; ct++) {
        int row = wc * 128 + ct * 16 + lc;
        int cc = (ks * 4 + lq) ^ (row & 7);
        fb[ct] = *(const bf16x8*)(Bs + row * 64 + cc * 8);
      }
#pragma unroll
      for (int rt = 0; rt < 4; rt++)
#pragma unroll
        for (int ct = 0; ct < 8; ct++)
          acc[rt][ct] = __builtin_amdgcn_mfma_f32_16x16x32_bf16(
              fa[rt], fb[ct], acc[rt][ct], 0, 0, 0);
    }
    __syncthreads();
  }

  // epilogue: dist = esq[j] - 2*dot; per-row argmin. ct ascending => ascending
  // j within this wave's half; strict '<' keeps lowest index on ties.
  float best[4][4]; int bidx[4][4];
#pragma unroll
  for (int rt = 0; rt < 4; rt++)
#pragma unroll
    for (int r = 0; r < 4; r++) { best[rt][r] = 3.4e38f; bidx[rt][r] = 0; }
#pragma unroll
  for (int rt = 0; rt < 4; rt++)
#pragma unroll
    for (int ct = 0; ct < 8; ct++) {
      int j = jb0 + wc * 128 + ct * 16 + lc;
      float es = esq[j];
#pragma unroll
      for (int r = 0; r < 4; r++) {
        float d = es - 2.0f * acc[rt][ct][r];
        if (d < best[rt][r]) { best[rt][r] = d; bidx[rt][r] = j; }
      }
    }

#pragma unroll
  for (int rt = 0; rt < 4; rt++) {
#pragma unroll
    for (int r = 0; r < 4; r++) {
      float bd = best[rt][r]; int bi = bidx[rt][r];
#pragma unroll
      for (int off = 1; off < 16; off <<= 1) {
        float od = __shfl_xor(bd, off, 64);
        int   oi = __shfl_xor(bi, off, 64);
        if (od < bd || (od == bd && oi < bi)) { bd = od; bi = oi; }
      }
      if (lc == 0) {
        int rloc = wr * 64 + rt * 16 + lq * 4 + r;
        sbd[wc][rloc] = bd;
        sbi[wc][rloc] = bi;
      }
    }
  }
  __syncthreads();
  // combine the two code-halves (wc=0 holds lower j: strict '<' keeps ties low)
  if (t < 128) {
    float b0 = sbd[0][t]; int i0 = sbi[0][t];
    float b1 = sbd[1][t]; int i1 = sbi[1][t];
    if (b1 < b0 || (b1 == b0 && i1 < i0)) { b0 = b1; i0 = i1; }
    int n = n0 + t;
    if (n < N) {
      pd[(size_t)n * 32 + blockIdx.y] = b0;
      pi[(size_t)n * 32 + blockIdx.y] = i0;
    }
  }
}

// reduce per-row partials over 32 code tiles -> idx, counts
__global__ void k_red(const float* __restrict__ pd, const int* __restrict__ pi,
                      int* __restrict__ idxb, float* __restrict__ counts, int N, int nct) {
  int n = blockIdx.x * 256 + threadIdx.x;
  if (n >= N) return;
  float bd = pd[(size_t)n * nct]; int bi = pi[(size_t)n * nct];
  for (int jt = 1; jt < nct; jt++) {
    float d = pd[(size_t)n * nct + jt]; int ii = pi[(size_t)n * nct + jt];
    if (d < bd || (d == bd && ii < bi)) { bd = d; bi = ii; }
  }
  idxb[n] = bi;
  atomicAdd(counts + bi, 1.0f);
}

// gather + bicubic upsample -> zu fp32 NHWC and zu2 compensated [hi,lo,hi]
__global__ void k_up(const float* __restrict__ emb, const int* __restrict__ idxb,
                     float* __restrict__ zu, short* __restrict__ zu2, int pn, int last) {
  int n = blockIdx.x, c = threadIdx.x;
  float acc;
  if (last) {
    acc = emb[(size_t)idxb[n] * 256 + c];
  } else {
    int b = n >> 8, hw = n & 255, h = hw >> 4, w = hw & 15;
    float scale = pn / 16.0f;
    float xh = (h + 0.5f) * scale - 0.5f; int fh = (int)floorf(xh);
    float xw = (w + 0.5f) * scale - 0.5f; int fw = (int)floorf(xw);
    int ph[4], pw[4]; float wh[4], wwt[4];
#pragma unroll
    for (int k = 0; k < 4; k++) {
      wh[k] = cubicw(xh - (float)(fh + k - 1));
      int pp = fh + k - 1; ph[k] = min(max(pp, 0), pn - 1);
      wwt[k] = cubicw(xw - (float)(fw + k - 1));
      pp = fw + k - 1; pw[k] = min(max(pp, 0), pn - 1);
    }
    acc = 0.0f;
#pragma unroll
    for (int kh = 0; kh < 4; kh++)
#pragma unroll
      for (int kw = 0; kw < 4; kw++) {
        int row = idxb[(n >> 8) * pn * pn + ph[kh] * pn + pw[kw]];
        acc += wh[kh] * wwt[kw] * emb[(size_t)row * 256 + c];
      }
  }
  zu[(size_t)n * 256 + c] = acc;
  short hi = f2bf(acc);
  short lo = f2bf(acc - bf2f(hi));
  zu2[(size_t)n * 768 + c]       = hi;
  zu2[(size_t)n * 768 + 256 + c] = lo;
  zu2[(size_t)n * 768 + 512 + c] = hi;
}

// 3x3 SAME conv as compensated-bf16 MFMA GEMM (K = 9 taps x 768) + fused
// bias + residual update + loss. Block: 64 px x 128 o, 4 waves, wave wv
// covers o-sub [wv*32, wv*32+32). Bs via global_load_lds + XOR swizzle;
// As manual (border zeroing) with LDA=72 pad. (unchanged from R7)
#define LDA 72
__global__ __launch_bounds__(256) void k_conv_mfma(
    const short* __restrict__ zu2, const short* __restrict__ wB2,
    const float* __restrict__ cb, const float* __restrict__ zu,
    float* __restrict__ zrest, float* __restrict__ out_loss, int si) {
  __shared__ short As[64 * LDA];
  __shared__ short Bs[128 * 64];
  __shared__ float red[256];
  int t = threadIdx.x, ln = t & 63, wv = t >> 6;
  int lc = ln & 15, lq = ln >> 4;
  int b = blockIdx.x >> 2, h0 = (blockIdx.x & 3) * 4;
  int o0 = blockIdx.y * 128;

  f32x4 acc[4][2];
#pragma unroll
  for (int rt = 0; rt < 4; rt++)
#pragma unroll
    for (int ct = 0; ct < 2; ct++) acc[rt][ct] = (f32x4)(0.0f);

  for (int kh = 0; kh < 3; kh++) {
    for (int kw = 0; kw < 3; kw++) {
      int tap = kh * 3 + kw;
      const short* bbase = wB2 + (((size_t)si * 9 + tap) * 256 + o0) * 768;
      const short* asrc[2]; bool aok[2]; int adst[2];
#pragma unroll
      for (int i = 0; i < 2; i++) {
        int G = i * 256 + t, row = G >> 3, cc = G & 7;
        int hs = h0 + (row >> 4) + kh - 1, ws = (row & 15) + kw - 1;
        aok[i] = (hs >= 0 && hs < 16 && ws >= 0 && ws < 16);
        int nsrc = aok[i] ? (b * 256 + hs * 16 + ws) : 0;
        asrc[i] = zu2 + (size_t)nsrc * 768 + cc * 8;
        adst[i] = row * LDA + cc * 8;
      }
      for (int kc = 0; kc < 12; kc++) {
#pragma unroll
        for (int i = 0; i < 2; i++) {
          uint4 v = make_uint4(0u, 0u, 0u, 0u);
          if (aok[i]) v = *(const uint4*)(asrc[i] + kc * 64);
          *(uint4*)(As + adst[i]) = v;
        }
#pragma unroll
        for (int i = 0; i < 4; i++) {
          int Lb = i * 256 + wv * 64;
          int L = Lb + ln;
          int row = L >> 3, cc = L & 7;
          int gc = cc ^ (row & 7);
          GLOAD_LDS(bbase + (size_t)row * 768 + kc * 64 + gc * 8, Bs + Lb * 8);
        }
        __syncthreads();
#pragma unroll
        for (int ks = 0; ks < 2; ks++) {
          bf16x8 fa[4], fb[2];
#pragma unroll
          for (int rt = 0; rt < 4; rt++)
            fa[rt] = *(const bf16x8*)(As + (rt * 16 + lc) * LDA + (ks * 4 + lq) * 8);
#pragma unroll
          for (int ct = 0; ct < 2; ct++) {
            int row = wv * 32 + ct * 16 + lc;
            int cc = (ks * 4 + lq) ^ (row & 7);
            fb[ct] = *(const bf16x8*)(Bs + row * 64 + cc * 8);
          }
#pragma unroll
          for (int rt = 0; rt < 4; rt++)
#pragma unroll
            for (int ct = 0; ct < 2; ct++)
              acc[rt][ct] = __builtin_amdgcn_mfma_f32_16x16x32_bf16(
                  fa[rt], fb[ct], acc[rt][ct], 0, 0, 0);
        }
        __syncthreads();
      }
    }
  }

  float lsum = 0.0f;
#pragma unroll
  for (int ct = 0; ct < 2; ct++) {
    int o = o0 + wv * 32 + ct * 16 + lc;
    float bias = cb[si * 256 + o];
#pragma unroll
    for (int rt = 0; rt < 4; rt++) {
#pragma unroll
      for (int r = 0; r < 4; r++) {
        int px = rt * 16 + lq * 4 + r;
        int n = b * 256 + (h0 + (px >> 4)) * 16 + (px & 15);
        size_t m = (size_t)n * 256 + o;
        float y = acc[rt][ct][r] + bias;
        float res = 0.5f * (zu[m] + y);
        float nv = zrest[m] - res;
        zrest[m] = nv;
        lsum += nv * nv;
      }
    }
  }
  red[t] = lsum;
  __syncthreads();
  for (int s = 128; s > 0; s >>= 1) { if (t < s) red[t] += red[t + s]; __syncthreads(); }
  if (t == 0) atomicAdd(out_loss, red[0] * (0.25f / (8.0f * 4194304.0f)));
}

// out NCHW = z - z_rest (z_hat_cum)
__global__ void k_out(const float* __restrict__ z, const float* __restrict__ zrest,
                      float* __restrict__ out) {
  int n = blockIdx.x, c = threadIdx.x;
  int b = n >> 8, hw = n & 255;
  size_t m = ((size_t)(b * 256 + c)) * 256 + hw;
  out[m] = z[m] - zrest[(size_t)n * 256 + c];
}

// ---------------- launch ----------------
extern "C" void kernel_launch(void* const* d_in, const int* in_sizes, int n_in,
                              void* d_out, int out_size, void* d_ws, size_t ws_size,
                              hipStream_t stream) {
  const float* z   = (const float*)d_in[0];
  const float* emb = (const float*)d_in[1];
  const float* cw  = (const float*)d_in[2];
  const float* cb  = (const float*)d_in[3];
  float* out = (float*)d_out;
  float* ws  = (float*)d_ws;

  // layout: 25,976,832 floats = 103.9 MB (proven-safe envelope: R1 used 112 MB)
  float* z_rest = ws;                        // 4,194,304
  float* zu     = ws + 4194304;              // 4,194,304
  float* esq    = ws + 8388608;              // 8,192
  short* A2     = (short*)(ws + 8396800);    // 16384*768 shorts = 6,291,456 floats
  short* zu2    = A2;                        // reuses A2 (free after dist)
  short* B2     = (short*)(ws + 14688256);   // 8192*768 shorts  = 3,145,728 floats
  short* wB2    = (short*)(ws + 17833984);   // 8*9*256*768 shorts = 7,077,888 floats
  float* pd     = ws + 24911872;             // 16384*32 = 524,288
  int*   pi     = (int*)(ws + 25436160);     // 524,288
  int*   idxb   = (int*)(ws + 25960448);     // 16,384

  const int pns[8] = {1, 2, 3, 4, 6, 8, 12, 16};

  k_zero<<<33, 256, 0, stream>>>(out + LOSS_OFF, 1 + NE);
  k_tr_in<<<16384, 256, 0, stream>>>(z, z_rest);
  k_prep_emb2<<<8192, 256, 0, stream>>>(emb, B2, esq);
  k_prep_wb<<<18432, 256, 0, stream>>>(cw, wB2);

  for (int si = 0; si < 8; si++) {
    int pn = pns[si];
    int N = 64 * pn * pn;
    if (si < 7)
      k_down_a2<<<dim3(pn * pn, 64), 256, 0, stream>>>(z_rest, A2, pn);
    else
      k_split_a2<<<16384, 256, 0, stream>>>(z_rest, A2);
    int rb = (N + 127) / 128;
    k_dist_mfma<<<dim3(rb, 32), 256, 0, stream>>>(A2, B2, esq, pd, pi, N);
    k_red<<<(N + 255) / 256, 256, 0, stream>>>(pd, pi, idxb, out + CNT_OFF, N, 32);
    k_up<<<16384, 256, 0, stream>>>(emb, idxb, zu, zu2, pn, si == 7 ? 1 : 0);
    k_conv_mfma<<<dim3(256, 2), 256, 0, stream>>>(zu2, wB2, cb, zu, z_rest,
                                                  out + LOSS_OFF, si);
  }
  k_out<<<16384, 256, 0, stream>>>(z, z_rest, out);
}